// Round 7
// baseline (530.360 us; speedup 1.0000x reference)
//
#include <hip/hip_runtime.h>

// Problem dims (fixed by setup_inputs)
#define BB 16
#define CR 1024
#define HWD 784     // 28*28
#define HW2 392     // HWD/2 (float2 units)
#define CS 256
#define SSZ 25
#define SP 28       // padded row length for kk/M/v
#define CI 512
#define NBLK 1024   // 4 blocks/CU (launch_bounds(256,4)); proven co-resident r1/r2.
                    // 128 blocks/XCD -> 64 per batch via pref split.

// Workspace layout (floats)
#define OFF_POOLED 0          // [B][CS*SSZ] = 102400
#define OFF_VP     102400     // [B][CR][SP] = 458752
#define OFF_MP     561152     // [B][CR][SP] = 458752
#define OFF_E0     1019904    // [B][S]      = 400
#define OFF_KK     1333904    // [B][CI][SP] = 229376
#define OFF_CTR    2000000    // counters: 136 x 64B slots
#define CTR_UINTS  (136 * 16)

// Coherence model (validated r3-fail + r6-pass):
//   - agent-scope relaxed RMWs: globally coherent -> all flags/claims.
//   - plain cached stores/loads: coherent within one XCD's L2 -> all DATA
//     producer->consumer pairs are same-XCD by construction. NO fences.
// Counter slots (64B each): gang[x]=x (x<8); per batch b: base 8+b*8 ->
//   tA0,dA0,tA1,dA1,tB,dB,tF (7 used). Monotone; memset per launch.

__device__ __forceinline__ unsigned rmw_inc(unsigned* p) {
    return __hip_atomic_fetch_add(p, 1u, __ATOMIC_RELAXED, __HIP_MEMORY_SCOPE_AGENT);
}
__device__ __forceinline__ unsigned aload(const unsigned* p) {
    return __hip_atomic_load(p, __ATOMIC_RELAXED, __HIP_MEMORY_SCOPE_AGENT);
}
__device__ __forceinline__ void gate(const unsigned* d, unsigned target) {
    __syncthreads();
    if (threadIdx.x == 0) {
        int spins = 0;
        while (aload(d) < target) {
            __builtin_amdgcn_s_sleep(4);
            if (++spins > (1 << 20)) break;        // safety valve: no hard-hang
        }
    }
    __syncthreads();
}

// kk/v projection body; pooled[b] staged in LDS
template <int NS>
__device__ __forceinline__ void proj_body(const float* __restrict__ wrow,
                                          const float* __restrict__ pb, int s0,
                                          float bias, float* __restrict__ dst,
                                          bool zpad) {
    float acc[NS];
#pragma unroll
    for (int i = 0; i < NS; ++i) acc[i] = 0.f;
    const float4* w4 = (const float4*)wrow;
#pragma unroll 4
    for (int c4 = 0; c4 < CS / 4; ++c4) {
        float4 w = w4[c4];
        const float* p = pb + c4 * 4 * SSZ + s0;
#pragma unroll
        for (int i = 0; i < NS; ++i)
            acc[i] = fmaf(w.x, p[i],
                     fmaf(w.y, p[SSZ + i],
                     fmaf(w.z, p[2 * SSZ + i],
                     fmaf(w.w, p[3 * SSZ + i], acc[i]))));
    }
#pragma unroll
    for (int i = 0; i < NS; ++i) dst[s0 + i] = acc[i] + bias;
    if (zpad) { dst[25] = 0.f; dst[26] = 0.f; dst[27] = 0.f; }
}

__global__ __launch_bounds__(256, 4) void mega(
    const float* __restrict__ xr, const float* __restrict__ xs,
    const float* __restrict__ Wq, const float* __restrict__ bq,
    const float* __restrict__ Wk, const float* __restrict__ bk,
    const float* __restrict__ Wv, const float* __restrict__ bv,
    const float* __restrict__ gm, float* __restrict__ out,
    float* __restrict__ ws)
{
    __shared__ __align__(16) float lds[6400];      // 25.6 KB -> 4 blocks/CU
    __shared__ unsigned comm;

    float* pooled = ws + OFF_POOLED;
    float* vp     = ws + OFF_VP;
    float* Mp     = ws + OFF_MP;
    float* e0g    = ws + OFF_E0;
    float* kk     = ws + OFF_KK;
    unsigned* ctr = (unsigned*)(ws + OFF_CTR);

    const int tid  = threadIdx.x;
    const int wave = tid >> 6, lane = tid & 63;

    // HW_REG_XCC_ID = hwreg 20, offset 0, size 4 (proven r6)
    const unsigned xcc = __builtin_amdgcn_s_getreg(20 | (0 << 6) | (3 << 11)) & 7u;

    if (tid == 0) comm = rmw_inc(ctr + xcc * 16);  // gang registration -> rank
    __syncthreads();
    const unsigned pref = comm & 1u;

    for (int pass = 0; pass < 2; ++pass) {
        const int b = 2 * (int)xcc + (int)(pref ^ (unsigned)pass);
        unsigned* cb = ctr + (8 + b * 8) * 16;     // tA0=+0,dA0=+16,tA1=+32,dA1=+48,
                                                   // tB=+64,dB=+80,tF=+96
        // ------------- PA0: pooled -> ws (8 tasks x 800 rows) -------------
        for (;;) {
            __syncthreads();
            if (tid == 0) comm = rmw_inc(cb + 0);
            __syncthreads();
            unsigned t = comm;
            if (t >= 8) break;
            const float* xsb = xs + (size_t)b * CS * SSZ * SSZ;
            int ebeg = (int)t * 800;
#pragma unroll
            for (int k = 0; k < 4; ++k) {
                int e = ebeg + k * 256 + tid;
                if (e < ebeg + 800) {
                    const float* row = xsb + (size_t)e * SSZ;
                    float s = 0.f;
#pragma unroll
                    for (int w = 0; w < SSZ; ++w) s += row[w];
                    pooled[(size_t)b * 6400 + e] = s * (1.0f / SSZ);
                }
            }
            __syncthreads();                       // vmcnt drain
            if (tid == 0) rmw_inc(cb + 16);
        }
        gate(cb + 16, 8);

        // ------------- PA1: kk/vp projections (48 tasks) ------------------
        for (;;) {
            __syncthreads();
            if (tid == 0) comm = rmw_inc(cb + 32);
            __syncthreads();
            unsigned t = comm;
            if (t >= 48) break;
            const float* pb = pooled + (size_t)b * 6400;
#pragma unroll
            for (int q = 0; q < 25; ++q) lds[tid + 256 * q] = pb[tid + 256 * q];
            __syncthreads();
            int rb = (int)t >> 3, sh = (int)t & 7;
            const float* wrow; float bias; float* dst;
            if (rb < 2) {
                int i = rb * 256 + tid;
                wrow = Wk + (size_t)i * CS; bias = bk[i];
                dst  = kk + ((size_t)b * CI + i) * SP;
            } else {
                int r = (rb - 2) * 256 + tid;
                wrow = Wv + (size_t)r * CS; bias = bv[r];
                dst  = vp + ((size_t)b * CR + r) * SP;
            }
            if (sh < 7) proj_body<3>(wrow, lds, 3 * sh, bias, dst, false);
            else        proj_body<4>(wrow, lds, 21,     bias, dst, true);
            __syncthreads();                       // vmcnt drain
            if (tid == 0) rmw_inc(cb + 48);
        }
        gate(cb + 48, 48);

        // ------------- PB: Mp (28 tasks, K=512) + e0 (task 28) ------------
        for (;;) {
            __syncthreads();
            if (tid == 0) comm = rmw_inc(cb + 64);
            __syncthreads();
            unsigned t = comm;
            if (t >= 29) break;
            if (t < 28) {
                int sc = (int)t >> 2, cq = (int)t & 3;
                int s0 = sc * 4;
                float* kst = lds;                  // [512][4] = 2048
                float* red = lds + 2048;           // [128][9] = 1152
                const float* kkb = kk + (size_t)b * CI * SP;
#pragma unroll
                for (int q = 0; q < 8; ++q) {
                    int d = tid + 256 * q;         // i=d>>2, col=d&3
                    kst[d] = kkb[(size_t)(d >> 2) * SP + s0 + (d & 3)];
                }
                __syncthreads();
                int half = tid >> 7, tq = tid & 127;
                int col = cq * 256 + 2 * tq;       // 2 consecutive c columns
                float acc[8];                      // [2c][4s]
#pragma unroll
                for (int e = 0; e < 8; ++e) acc[e] = 0.f;
                const float4* kst4 = (const float4*)kst;
                int i0 = half * 256;
#pragma unroll 4
                for (int i = 0; i < 256; ++i) {
                    float2 w = *(const float2*)(Wq + (size_t)(i0 + i) * CR + col);
                    float4 k = kst4[i0 + i];
                    acc[0] = fmaf(w.x, k.x, acc[0]);
                    acc[1] = fmaf(w.x, k.y, acc[1]);
                    acc[2] = fmaf(w.x, k.z, acc[2]);
                    acc[3] = fmaf(w.x, k.w, acc[3]);
                    acc[4] = fmaf(w.y, k.x, acc[4]);
                    acc[5] = fmaf(w.y, k.y, acc[5]);
                    acc[6] = fmaf(w.y, k.z, acc[6]);
                    acc[7] = fmaf(w.y, k.w, acc[7]);
                }
                if (half == 1) {
#pragma unroll
                    for (int j = 0; j < 8; ++j) red[tq * 9 + j] = acc[j];
                }
                __syncthreads();
                if (half == 0) {
#pragma unroll
                    for (int j = 0; j < 8; ++j) acc[j] += red[tq * 9 + j];
                    float4 o0 = make_float4(acc[0], acc[1], acc[2], acc[3]);
                    float4 o1 = make_float4(acc[4], acc[5], acc[6], acc[7]);
                    *(float4*)&Mp[((size_t)(b << 10) + col) * SP + s0] = o0;
                    *(float4*)&Mp[((size_t)(b << 10) + col + 1) * SP + s0] = o1;
                }
            } else {
                const float* kb = kk + (size_t)b * CI * SP;
                for (int s = wave; s < SSZ; s += 4) {
                    float a = 0.f;
#pragma unroll
                    for (int k2 = 0; k2 < CI / 64; ++k2) {
                        int i = lane + 64 * k2;
                        a = fmaf(bq[i], kb[(size_t)i * SP + s], a);
                    }
#pragma unroll
                    for (int off = 32; off > 0; off >>= 1) a += __shfl_down(a, off);
                    if (lane == 0) e0g[b * SSZ + s] = a;
                }
            }
            __syncthreads();                       // vmcnt drain
            if (tid == 0) rmw_inc(cb + 80);
        }
        gate(cb + 80, 29);

        // ------------- PF: energy + softmax + out (49 tile-tasks) ---------
        // n-tile = 8 float2 lanes (49*8 = 392 exactly, no tail). nl=tid&7,
        // cg=tid>>3 (32 groups x 32 rows). Energy in regs -> shfl_xor reduce
        // over cg-slice bits (8,16,32) -> 6.4KB cross-wave LDS -> softmax by
        // 8 lanes -> out pass over same 32 rows (x_rgb L1-warm).
        for (;;) {
            __syncthreads();
            if (tid == 0) comm = rmw_inc(cb + 96);
            __syncthreads();
            unsigned t = comm;
            if (t >= 49) break;
            int nl = tid & 7, cg = tid >> 3;
            int n2 = (int)t * 8 + nl;              // < 392 always
            const float2* x2 = (const float2*)(xr + (size_t)b * CR * HWD);

            float a0[SSZ], a1[SSZ];
#pragma unroll
            for (int s = 0; s < SSZ; ++s) { a0[s] = 0.f; a1[s] = 0.f; }
            const int c0 = cg * 32;
            for (int c = c0; c < c0 + 32; c += 4) {
                float2 xv[4];
#pragma unroll
                for (int u = 0; u < 4; ++u)
                    xv[u] = x2[(size_t)(c + u) * HW2 + n2];
#pragma unroll
                for (int u = 0; u < 4; ++u) {
                    const float4* mr = (const float4*)&Mp[((size_t)(b << 10) + c + u) * SP];
#pragma unroll
                    for (int j = 0; j < 6; ++j) {
                        float4 m = mr[j];
                        a0[4 * j + 0] = fmaf(xv[u].x, m.x, a0[4 * j + 0]);
                        a0[4 * j + 1] = fmaf(xv[u].x, m.y, a0[4 * j + 1]);
                        a0[4 * j + 2] = fmaf(xv[u].x, m.z, a0[4 * j + 2]);
                        a0[4 * j + 3] = fmaf(xv[u].x, m.w, a0[4 * j + 3]);
                        a1[4 * j + 0] = fmaf(xv[u].y, m.x, a1[4 * j + 0]);
                        a1[4 * j + 1] = fmaf(xv[u].y, m.y, a1[4 * j + 1]);
                        a1[4 * j + 2] = fmaf(xv[u].y, m.z, a1[4 * j + 2]);
                        a1[4 * j + 3] = fmaf(xv[u].y, m.w, a1[4 * j + 3]);
                    }
                    float m24 = mr[6].x;
                    a0[24] = fmaf(xv[u].x, m24, a0[24]);
                    a1[24] = fmaf(xv[u].y, m24, a1[24]);
                }
            }
            // intra-wave reduce across the 8 cg-slices (lane bits 3,4,5)
#pragma unroll
            for (int s = 0; s < SSZ; ++s) {
                a0[s] += __shfl_xor(a0[s], 8);
                a0[s] += __shfl_xor(a0[s], 16);
                a0[s] += __shfl_xor(a0[s], 32);
                a1[s] += __shfl_xor(a1[s], 8);
                a1[s] += __shfl_xor(a1[s], 16);
                a1[s] += __shfl_xor(a1[s], 32);
            }
            float2* wrp = (float2*)lds;            // [4][8][25] = 6.4 KB
            if (lane < 8) {
#pragma unroll
                for (int s = 0; s < SSZ; ++s)
                    wrp[(wave * 8 + nl) * SSZ + s] = make_float2(a0[s], a1[s]);
            }
            __syncthreads();
            float2* att2 = wrp + 4 * 8 * SSZ;      // [8][25]
            if (tid < 8) {
                float ex[SSZ], ey[SSZ];
#pragma unroll
                for (int s = 0; s < SSZ; ++s) {
                    float v = e0g[b * SSZ + s];
                    float2 p0 = wrp[(0 * 8 + tid) * SSZ + s];
                    float2 p1 = wrp[(1 * 8 + tid) * SSZ + s];
                    float2 p2 = wrp[(2 * 8 + tid) * SSZ + s];
                    float2 p3 = wrp[(3 * 8 + tid) * SSZ + s];
                    ex[s] = v + p0.x + p1.x + p2.x + p3.x;
                    ey[s] = v + p0.y + p1.y + p2.y + p3.y;
                }
                float mx = ex[0], my = ey[0];
#pragma unroll
                for (int s = 1; s < SSZ; ++s) { mx = fmaxf(mx, ex[s]); my = fmaxf(my, ey[s]); }
                float sx = 0.f, sy = 0.f;
#pragma unroll
                for (int s = 0; s < SSZ; ++s) {
                    ex[s] = __expf(ex[s] - mx); sx += ex[s];
                    ey[s] = __expf(ey[s] - my); sy += ey[s];
                }
                float ix = 1.0f / sx, iy = 1.0f / sy;
#pragma unroll
                for (int s = 0; s < SSZ; ++s)
                    att2[tid * SSZ + s] = make_float2(ex[s] * ix, ey[s] * iy);
            }
            __syncthreads();
#pragma unroll
            for (int s = 0; s < SSZ; ++s) {
                float2 av = att2[nl * SSZ + s];
                a0[s] = av.x; a1[s] = av.y;
            }
            float g = gm[0];
            float2* o2 = (float2*)(out + (size_t)b * CR * HWD);
            const int r0 = cg * 32;
            for (int r = r0; r < r0 + 32; r += 2) {
                float2 xva = x2[(size_t)r * HW2 + n2];
                float2 xvb = x2[(size_t)(r + 1) * HW2 + n2];
                const float4* vra = (const float4*)&vp[((size_t)(b << 10) + r) * SP];
                const float4* vrb = (const float4*)&vp[((size_t)(b << 10) + r + 1) * SP];
                float d0a = 0.f, d1a = 0.f, d0b = 0.f, d1b = 0.f;
#pragma unroll
                for (int j = 0; j < 6; ++j) {
                    float4 va = vra[j], vb = vrb[j];
                    d0a = fmaf(va.x, a0[4 * j + 0], d0a);
                    d0a = fmaf(va.y, a0[4 * j + 1], d0a);
                    d0a = fmaf(va.z, a0[4 * j + 2], d0a);
                    d0a = fmaf(va.w, a0[4 * j + 3], d0a);
                    d1a = fmaf(va.x, a1[4 * j + 0], d1a);
                    d1a = fmaf(va.y, a1[4 * j + 1], d1a);
                    d1a = fmaf(va.z, a1[4 * j + 2], d1a);
                    d1a = fmaf(va.w, a1[4 * j + 3], d1a);
                    d0b = fmaf(vb.x, a0[4 * j + 0], d0b);
                    d0b = fmaf(vb.y, a0[4 * j + 1], d0b);
                    d0b = fmaf(vb.z, a0[4 * j + 2], d0b);
                    d0b = fmaf(vb.w, a0[4 * j + 3], d0b);
                    d1b = fmaf(vb.x, a1[4 * j + 0], d1b);
                    d1b = fmaf(vb.y, a1[4 * j + 1], d1b);
                    d1b = fmaf(vb.z, a1[4 * j + 2], d1b);
                    d1b = fmaf(vb.w, a1[4 * j + 3], d1b);
                }
                d0a = fmaf(vra[6].x, a0[24], d0a);
                d1a = fmaf(vra[6].x, a1[24], d1a);
                d0b = fmaf(vrb[6].x, a0[24], d0b);
                d1b = fmaf(vrb[6].x, a1[24], d1b);
                o2[(size_t)r * HW2 + n2] =
                    make_float2(fmaf(g, d0a, xva.x), fmaf(g, d1a, xva.y));
                o2[(size_t)(r + 1) * HW2 + n2] =
                    make_float2(fmaf(g, d0b, xvb.x), fmaf(g, d1b, xvb.y));
            }
        }
    }
}

extern "C" void kernel_launch(void* const* d_in, const int* in_sizes, int n_in,
                              void* d_out, int out_size, void* d_ws, size_t ws_size,
                              hipStream_t stream) {
    const float* x_rgb  = (const float*)d_in[0];
    const float* x_skel = (const float*)d_in[1];
    const float* Wq     = (const float*)d_in[2];
    const float* bq     = (const float*)d_in[3];
    const float* Wk     = (const float*)d_in[4];
    const float* bk     = (const float*)d_in[5];
    const float* Wv     = (const float*)d_in[6];
    const float* bv     = (const float*)d_in[7];
    const float* gamma  = (const float*)d_in[8];
    float* out = (float*)d_out;
    float* ws  = (float*)d_ws;

    // Zero all gang/task/done counters every replay (stream-ordered, capturable).
    hipMemsetAsync(ws + OFF_CTR, 0, CTR_UINTS * sizeof(unsigned), stream);

    hipLaunchKernelGGL(mega, dim3(NBLK), dim3(256), 0, stream,
                       x_rgb, x_skel, Wq, bq, Wk, bk, Wv, bv, gamma, out, ws);
}

// Round 8
// 240.781 us; speedup vs baseline: 2.2027x; 2.2027x over previous
//
#include <hip/hip_runtime.h>

// Problem dims (fixed by setup_inputs)
#define BB 16
#define CR 1024
#define HWD 784     // 28*28
#define HW2 392     // HWD/2 (float2 units)
#define CS 256
#define SSZ 25
#define SP 28       // padded row length for kk/M/v
#define CI 512
#define NBLK 512    // 2 blocks/CU (launch_bounds(256,2)); proven co-resident r4-r6.
                    // 64 blocks/XCD -> ~32 per batch via pref split.

// Workspace layout (floats)
#define OFF_POOLED 0          // [B][CS*SSZ] = 102400
#define OFF_VP     102400     // [B][CR][SP] = 458752
#define OFF_MP     561152     // [B][CR][SP] = 458752
#define OFF_E0     1019904    // [B][S]      = 400
#define OFF_KK     1333904    // [B][CI][SP] = 229376
#define OFF_CTR    2000000    // counters: 200 x 64B slots
#define CTR_UINTS  (200 * 16)

// Coherence model (validated r3-fail + r6-pass):
//   - agent-scope relaxed RMWs: globally coherent -> all flags/claims.
//   - plain cached stores/loads: coherent within one XCD's L2 -> all DATA
//     producer->consumer pairs are same-XCD by construction. NO fences.
// Counter slots (64B each): gang[x]=x (x<8); per batch b: base 8+b*8 ->
//   tA0=+0,dA0=+1,tA1=+2,dA1=+3,tB=+4,dB=+5,tF=+6. Monotone; memset/launch.
// Monotone claims also give emergent work-stealing: a sub-gang entering its
// second batch finds exhausted counters, skips, and helps finish later phases.

__device__ __forceinline__ unsigned rmw_inc(unsigned* p) {
    return __hip_atomic_fetch_add(p, 1u, __ATOMIC_RELAXED, __HIP_MEMORY_SCOPE_AGENT);
}
__device__ __forceinline__ unsigned aload(const unsigned* p) {
    return __hip_atomic_load(p, __ATOMIC_RELAXED, __HIP_MEMORY_SCOPE_AGENT);
}
__device__ __forceinline__ void gate(const unsigned* d, unsigned target) {
    __syncthreads();
    if (threadIdx.x == 0) {
        int spins = 0;
        while (aload(d) < target) {
            __builtin_amdgcn_s_sleep(1);           // 64cyc poll granularity
            if (++spins > (1 << 22)) break;        // safety valve: no hard-hang
        }
    }
    __syncthreads();
}

// kk/v projection body; pooled[b] staged in LDS
template <int NS>
__device__ __forceinline__ void proj_body(const float* __restrict__ wrow,
                                          const float* __restrict__ pb, int s0,
                                          float bias, float* __restrict__ dst,
                                          bool zpad) {
    float acc[NS];
#pragma unroll
    for (int i = 0; i < NS; ++i) acc[i] = 0.f;
    const float4* w4 = (const float4*)wrow;
#pragma unroll 4
    for (int c4 = 0; c4 < CS / 4; ++c4) {
        float4 w = w4[c4];
        const float* p = pb + c4 * 4 * SSZ + s0;
#pragma unroll
        for (int i = 0; i < NS; ++i)
            acc[i] = fmaf(w.x, p[i],
                     fmaf(w.y, p[SSZ + i],
                     fmaf(w.z, p[2 * SSZ + i],
                     fmaf(w.w, p[3 * SSZ + i], acc[i]))));
    }
#pragma unroll
    for (int i = 0; i < NS; ++i) dst[s0 + i] = acc[i] + bias;
    if (zpad) { dst[25] = 0.f; dst[26] = 0.f; dst[27] = 0.f; }
}

__global__ __launch_bounds__(256, 2) void mega(
    const float* __restrict__ xr, const float* __restrict__ xs,
    const float* __restrict__ Wq, const float* __restrict__ bq,
    const float* __restrict__ Wk, const float* __restrict__ bk,
    const float* __restrict__ Wv, const float* __restrict__ bv,
    const float* __restrict__ gm, float* __restrict__ out,
    float* __restrict__ ws)
{
    __shared__ __align__(16) float lds[13600];     // 54.4 KB; 2 blocks/CU
    __shared__ unsigned comm;

    float* pooled = ws + OFF_POOLED;
    float* vp     = ws + OFF_VP;
    float* Mp     = ws + OFF_MP;
    float* e0g    = ws + OFF_E0;
    float* kk     = ws + OFF_KK;
    unsigned* ctr = (unsigned*)(ws + OFF_CTR);

    const int tid  = threadIdx.x;
    const int wave = tid >> 6, lane = tid & 63;

    // HW_REG_XCC_ID = hwreg 20, offset 0, size 4 (proven r6)
    const unsigned xcc = __builtin_amdgcn_s_getreg(20 | (0 << 6) | (3 << 11)) & 7u;

    if (tid == 0) comm = rmw_inc(ctr + xcc * 16);  // gang registration -> rank
    __syncthreads();
    const unsigned pref = comm & 1u;

    for (int pass = 0; pass < 2; ++pass) {
        const int b = 2 * (int)xcc + (int)(pref ^ (unsigned)pass);
        unsigned* cb = ctr + (8 + b * 8) * 16;     // +0..+6 slots x16 uints

        // ------------- PA0: pooled -> ws (25 tasks x 256 rows, coalesced) ------
        // Stage 256 (c,s)-rows (6400 floats) as 1600 float4, then row-sum from
        // LDS (stride 25, gcd(25,32)=1 -> conflict-free). Replaces r6's 24x
        // redundant scalar-scatter recompute (~13us/batch).
        for (;;) {
            __syncthreads();
            if (tid == 0) comm = rmw_inc(cb + 0);
            __syncthreads();
            unsigned t = comm;
            if (t >= 25) break;
            const float4* src4 = (const float4*)(xs + (size_t)b * 160000 +
                                                 (size_t)t * 6400);
            float4* l4 = (float4*)lds;
#pragma unroll
            for (int q = 0; q < 7; ++q) {
                int ix = tid + 256 * q;
                if (ix < 1600) l4[ix] = src4[ix];
            }
            __syncthreads();
            const float* row = lds + tid * SSZ;
            float s = 0.f;
#pragma unroll
            for (int w = 0; w < SSZ; ++w) s += row[w];
            pooled[(size_t)b * 6400 + t * 256 + tid] = s * (1.0f / SSZ);
            __syncthreads();                       // vmcnt drain + LDS reuse safe
            if (tid == 0) rmw_inc(cb + 16);
        }
        gate(cb + 16, 25);

        // ------------- PA1: kk/vp projections (24 tasks, r6 geometry) ----------
        for (;;) {
            __syncthreads();
            if (tid == 0) comm = rmw_inc(cb + 32);
            __syncthreads();
            unsigned t = comm;
            if (t >= 24) break;
            const float4* pb4 = (const float4*)(pooled + (size_t)b * 6400);
            float4* l4 = (float4*)lds;
#pragma unroll
            for (int q = 0; q < 7; ++q) {
                int ix = tid + 256 * q;
                if (ix < 1600) l4[ix] = pb4[ix];
            }
            __syncthreads();
            int rb = (int)t >> 2, sh = (int)t & 3;
            const float* wrow; float bias; float* dst;
            if (rb < 2) {
                int i = rb * 256 + tid;
                wrow = Wk + (size_t)i * CS; bias = bk[i];
                dst  = kk + ((size_t)b * CI + i) * SP;
            } else {
                int r = (rb - 2) * 256 + tid;
                wrow = Wv + (size_t)r * CS; bias = bv[r];
                dst  = vp + ((size_t)b * CR + r) * SP;
            }
            int s0 = sh * 7;
            if (sh < 3) proj_body<7>(wrow, lds, s0, bias, dst, false);
            else        proj_body<4>(wrow, lds, s0, bias, dst, true);
            __syncthreads();                       // vmcnt drain
            if (tid == 0) rmw_inc(cb + 48);
        }
        gate(cb + 48, 24);

        // ------------- PB: Mp (14 tasks, K=512) + e0 (task 14) -----------------
        for (;;) {
            __syncthreads();
            if (tid == 0) comm = rmw_inc(cb + 64);
            __syncthreads();
            unsigned t = comm;
            if (t >= 15) break;
            if (t < 14) {
                int sc = (int)t % 7, chalf = (int)t / 7;
                int s0 = sc * 4;
                float* kst = lds;                  // [512][4] = 2048
                float* red = lds + 2048;           // [128][17] = 2176
                const float* kkb = kk + (size_t)b * CI * SP;
#pragma unroll
                for (int q = 0; q < 8; ++q) {
                    int d = tid + 256 * q;         // i=d>>2, col=d&3
                    kst[d] = kkb[(size_t)(d >> 2) * SP + s0 + (d & 3)];
                }
                __syncthreads();
                int half = tid >> 7, tq = tid & 127;
                int cq = chalf * 512 + 4 * tq;
                float acc[16];
#pragma unroll
                for (int e = 0; e < 16; ++e) acc[e] = 0.f;
                const float4* kst4 = (const float4*)kst;
                int i0 = half * 256;
#pragma unroll 4
                for (int i = 0; i < 256; ++i) {
                    float4 w = *(const float4*)(Wq + (size_t)(i0 + i) * CR + cq);
                    float4 k = kst4[i0 + i];
#pragma unroll
                    for (int cl = 0; cl < 4; ++cl) {
                        float wc = cl == 0 ? w.x : cl == 1 ? w.y : cl == 2 ? w.z : w.w;
                        acc[cl * 4 + 0] = fmaf(wc, k.x, acc[cl * 4 + 0]);
                        acc[cl * 4 + 1] = fmaf(wc, k.y, acc[cl * 4 + 1]);
                        acc[cl * 4 + 2] = fmaf(wc, k.z, acc[cl * 4 + 2]);
                        acc[cl * 4 + 3] = fmaf(wc, k.w, acc[cl * 4 + 3]);
                    }
                }
                if (half == 1) {
#pragma unroll
                    for (int j = 0; j < 16; ++j) red[tq * 17 + j] = acc[j];
                }
                __syncthreads();
                if (half == 0) {
#pragma unroll
                    for (int j = 0; j < 16; ++j) acc[j] += red[tq * 17 + j];
#pragma unroll
                    for (int cl = 0; cl < 4; ++cl) {
                        float4 o;
                        o.x = acc[cl * 4 + 0]; o.y = acc[cl * 4 + 1];
                        o.z = acc[cl * 4 + 2]; o.w = acc[cl * 4 + 3];
                        *(float4*)&Mp[((size_t)(b << 10) + cq + cl) * SP + s0] = o;
                    }
                }
            } else {
                const float* kb = kk + (size_t)b * CI * SP;
                for (int s = wave; s < SSZ; s += 4) {
                    float a = 0.f;
#pragma unroll
                    for (int k2 = 0; k2 < CI / 64; ++k2) {
                        int i = lane + 64 * k2;
                        a = fmaf(bq[i], kb[(size_t)i * SP + s], a);
                    }
#pragma unroll
                    for (int off = 32; off > 0; off >>= 1) a += __shfl_down(a, off);
                    if (lane == 0) e0g[b * SSZ + s] = a;
                }
            }
            __syncthreads();                       // vmcnt drain
            if (tid == 0) rmw_inc(cb + 80);
        }
        gate(cb + 80, 15);

        // ------------- PF: energy + softmax + out (25 tile-tasks, r6 geom) -----
        // 16-float2-lane tiles (128B rows: cache-exact). cg=tid>>4 (16 groups x
        // 64 rows), nl=tid&15. x-prefetch deepened 4->8.
        for (;;) {
            __syncthreads();
            if (tid == 0) comm = rmw_inc(cb + 96);
            __syncthreads();
            unsigned t = comm;
            if (t >= 25) break;
            int cg = tid >> 4, nl = tid & 15;
            int n2 = (int)t * 16 + nl;
            bool valid = n2 < HW2;
            int n2c = valid ? n2 : 0;
            const float2* x2 = (const float2*)(xr + (size_t)b * CR * HWD);

            float a0[SSZ], a1[SSZ];
#pragma unroll
            for (int s = 0; s < SSZ; ++s) { a0[s] = 0.f; a1[s] = 0.f; }
            const int c0 = cg * 64;
            for (int c = c0; c < c0 + 64; c += 8) {
                float2 xv[8];
#pragma unroll
                for (int u = 0; u < 8; ++u)
                    xv[u] = x2[(size_t)(c + u) * HW2 + n2c];
#pragma unroll
                for (int u = 0; u < 8; ++u) {
                    const float4* mr = (const float4*)&Mp[((size_t)(b << 10) + c + u) * SP];
#pragma unroll
                    for (int j = 0; j < 6; ++j) {
                        float4 m = mr[j];
                        a0[4 * j + 0] = fmaf(xv[u].x, m.x, a0[4 * j + 0]);
                        a0[4 * j + 1] = fmaf(xv[u].x, m.y, a0[4 * j + 1]);
                        a0[4 * j + 2] = fmaf(xv[u].x, m.z, a0[4 * j + 2]);
                        a0[4 * j + 3] = fmaf(xv[u].x, m.w, a0[4 * j + 3]);
                        a1[4 * j + 0] = fmaf(xv[u].y, m.x, a1[4 * j + 0]);
                        a1[4 * j + 1] = fmaf(xv[u].y, m.y, a1[4 * j + 1]);
                        a1[4 * j + 2] = fmaf(xv[u].y, m.z, a1[4 * j + 2]);
                        a1[4 * j + 3] = fmaf(xv[u].y, m.w, a1[4 * j + 3]);
                    }
                    float m24 = mr[6].x;
                    a0[24] = fmaf(xv[u].x, m24, a0[24]);
                    a1[24] = fmaf(xv[u].y, m24, a1[24]);
                }
            }
            float2* part = (float2*)lds;           // [256][25]
#pragma unroll
            for (int s = 0; s < SSZ; ++s) part[tid * SSZ + s] = make_float2(a0[s], a1[s]);
            __syncthreads();

            float2* att2 = part + 6400;            // [16][25]
            if (tid < 16) {
                float ex[SSZ], ey[SSZ];
#pragma unroll
                for (int s = 0; s < SSZ; ++s) { float v = e0g[b * SSZ + s]; ex[s] = v; ey[s] = v; }
                for (int g16 = 0; g16 < 16; ++g16) {
#pragma unroll
                    for (int s = 0; s < SSZ; ++s) {
                        float2 p = part[(g16 * 16 + tid) * SSZ + s];
                        ex[s] += p.x; ey[s] += p.y;
                    }
                }
                float mx = ex[0], my = ey[0];
#pragma unroll
                for (int s = 1; s < SSZ; ++s) { mx = fmaxf(mx, ex[s]); my = fmaxf(my, ey[s]); }
                float sx = 0.f, sy = 0.f;
#pragma unroll
                for (int s = 0; s < SSZ; ++s) {
                    ex[s] = __expf(ex[s] - mx); sx += ex[s];
                    ey[s] = __expf(ey[s] - my); sy += ey[s];
                }
                float ix = 1.0f / sx, iy = 1.0f / sy;
#pragma unroll
                for (int s = 0; s < SSZ; ++s)
                    att2[tid * SSZ + s] = make_float2(ex[s] * ix, ey[s] * iy);
            }
            __syncthreads();
#pragma unroll
            for (int s = 0; s < SSZ; ++s) {
                float2 av = att2[nl * SSZ + s];
                a0[s] = av.x; a1[s] = av.y;
            }
            float g = gm[0];
            float2* o2 = (float2*)(out + (size_t)b * CR * HWD);
            const int r0 = cg * 64;
            for (int r = r0; r < r0 + 64; r += 2) {
                float2 xva = x2[(size_t)r * HW2 + n2c];
                float2 xvb = x2[(size_t)(r + 1) * HW2 + n2c];
                const float4* vra = (const float4*)&vp[((size_t)(b << 10) + r) * SP];
                const float4* vrb = (const float4*)&vp[((size_t)(b << 10) + r + 1) * SP];
                float d0a = 0.f, d1a = 0.f, d0b = 0.f, d1b = 0.f;
#pragma unroll
                for (int j = 0; j < 6; ++j) {
                    float4 va = vra[j], vb = vrb[j];
                    d0a = fmaf(va.x, a0[4 * j + 0], d0a);
                    d0a = fmaf(va.y, a0[4 * j + 1], d0a);
                    d0a = fmaf(va.z, a0[4 * j + 2], d0a);
                    d0a = fmaf(va.w, a0[4 * j + 3], d0a);
                    d1a = fmaf(va.x, a1[4 * j + 0], d1a);
                    d1a = fmaf(va.y, a1[4 * j + 1], d1a);
                    d1a = fmaf(va.z, a1[4 * j + 2], d1a);
                    d1a = fmaf(va.w, a1[4 * j + 3], d1a);
                    d0b = fmaf(vb.x, a0[4 * j + 0], d0b);
                    d0b = fmaf(vb.y, a0[4 * j + 1], d0b);
                    d0b = fmaf(vb.z, a0[4 * j + 2], d0b);
                    d0b = fmaf(vb.w, a0[4 * j + 3], d0b);
                    d1b = fmaf(vb.x, a1[4 * j + 0], d1b);
                    d1b = fmaf(vb.y, a1[4 * j + 1], d1b);
                    d1b = fmaf(vb.z, a1[4 * j + 2], d1b);
                    d1b = fmaf(vb.w, a1[4 * j + 3], d1b);
                }
                d0a = fmaf(vra[6].x, a0[24], d0a);
                d1a = fmaf(vra[6].x, a1[24], d1a);
                d0b = fmaf(vrb[6].x, a0[24], d0b);
                d1b = fmaf(vrb[6].x, a1[24], d1b);
                if (valid) {
                    o2[(size_t)r * HW2 + n2] =
                        make_float2(fmaf(g, d0a, xva.x), fmaf(g, d1a, xva.y));
                    o2[(size_t)(r + 1) * HW2 + n2] =
                        make_float2(fmaf(g, d0b, xvb.x), fmaf(g, d1b, xvb.y));
                }
            }
        }
    }
}

extern "C" void kernel_launch(void* const* d_in, const int* in_sizes, int n_in,
                              void* d_out, int out_size, void* d_ws, size_t ws_size,
                              hipStream_t stream) {
    const float* x_rgb  = (const float*)d_in[0];
    const float* x_skel = (const float*)d_in[1];
    const float* Wq     = (const float*)d_in[2];
    const float* bq     = (const float*)d_in[3];
    const float* Wk     = (const float*)d_in[4];
    const float* bk     = (const float*)d_in[5];
    const float* Wv     = (const float*)d_in[6];
    const float* bv     = (const float*)d_in[7];
    const float* gamma  = (const float*)d_in[8];
    float* out = (float*)d_out;
    float* ws  = (float*)d_ws;

    // Zero all gang/task/done counters every replay (stream-ordered, capturable).
    hipMemsetAsync(ws + OFF_CTR, 0, CTR_UINTS * sizeof(unsigned), stream);

    hipLaunchKernelGGL(mega, dim3(NBLK), dim3(256), 0, stream,
                       x_rgb, x_skel, Wq, bq, Wk, bk, Wv, bv, gamma, out, ws);
}